// Round 6
// baseline (37.868 us; speedup 1.0000x reference)
//
#include <hip/hip_runtime.h>

typedef _Float16 f16x8 __attribute__((ext_vector_type(8)));
typedef float f32x16 __attribute__((ext_vector_type(16)));

#define TRUNC_VAL 2.0f
#define TPS 16     // A-tiles per segment (LDS-resident); NSEG = NT/TPS
#define NSEG 32    // segments for N=16384
#define WPB 4      // waves per block
#define BPT 8      // query (B) tiles per wave: 8 MFMAs per A-frag read

// ---------------------------------------------------------------------------
// R6: identical to R5 except __launch_bounds__(256, 1) on the chamfer kernel.
// R5 post-mortem: ILP-4 grouping gained 23% but the inner loop needs ~240
// VGPRs (8 live f32x16 + b[8] + m + zero) and (256,2) capped the unified
// file at 256 -> allocator spill/AGPR-shuttle traffic right at the boundary.
// (256,1) opens the 512-reg unified file; HW still co-resides 2 waves/SIMD
// when the kernel lands under 256 regs, so we lose the traffic, not occupancy.
// R2 lesson: no device-scope fences. R3/R4 lesson: launch count is not the
// binding term.
//
// Fragment layout (identical values to the verified pack, absmax 0.0):
//   v_mfma_f32_32x32x16_f16, lane l of tile t at frag[t*64+l],
//   row/col = l&31, k = 8*(l>>5)+i.  hi/lo fp16 split, ~22-bit precision:
//   A (target j): [xh yh zh | xh yh zh | xl yl zl | wh wl | 0...] w=-0.5||y||^2
//   B (query  i): [xh yh zh | xl yl zl | xh yh zh | 1  1  | 0...]
//   => dot = q.y - 0.5||y||^2
// ---------------------------------------------------------------------------
__global__ __launch_bounds__(64 * WPB, 1) void chamfer_mfma_kernel(
    const float* __restrict__ fw, const float* __restrict__ bwv,
    const float* __restrict__ p0, const float* __restrict__ p1,
    float* __restrict__ Pfw, float* __restrict__ Pbw,
    float* __restrict__ out, int N) {
    __shared__ f16x8 Alds[TPS * 64];           // 16 KB: the block's A segment

    int lane = threadIdx.x & 63;
    int wave = threadIdx.x >> 6;
    int r    = lane & 31;
    bool hi  = lane >= 32;
    int col  = blockIdx.x * WPB + wave;        // query column: 256 queries/wave
    int seg  = blockIdx.y;                     // target segment (block-shared)
    int z    = blockIdx.z;
    float* __restrict__ P = z ? Pbw : Pfw;

    // out[0] = 0 once per launch; stream-ordered before reduce's atomicAdds.
    if (threadIdx.x == 0 && blockIdx.x == 0 && blockIdx.y == 0 && z == 0)
        out[0] = 0.0f;

    // ---- build B fragments in registers (once per wave) ----
    f16x8 b[BPT];
    #pragma unroll
    for (int c = 0; c < BPT; ++c) {
        int i = (col * BPT + c) * 32 + r;
        float qx = p0[3*i]   + fw[3*i];
        float qy = p0[3*i+1] + fw[3*i+1];
        float qz = p0[3*i+2] + fw[3*i+2];
        if (z) { qx -= bwv[3*i]; qy -= bwv[3*i+1]; qz -= bwv[3*i+2]; }
        _Float16 xh = (_Float16)qx, yh = (_Float16)qy, zh = (_Float16)qz;
        _Float16 xl = (_Float16)(qx - (float)xh);
        _Float16 yl = (_Float16)(qy - (float)yh);
        _Float16 zl = (_Float16)(qz - (float)zh);
        f16x8 o;
        if (!hi) { o[0]=xh; o[1]=yh; o[2]=zh; o[3]=xl; o[4]=yl; o[5]=zl; o[6]=xh; o[7]=yh; }
        else {
            o[0]=zh; o[1]=(_Float16)1.0f; o[2]=(_Float16)1.0f;
            o[3]=(_Float16)0.0f; o[4]=(_Float16)0.0f; o[5]=(_Float16)0.0f;
            o[6]=(_Float16)0.0f; o[7]=(_Float16)0.0f;
        }
        b[c] = o;
    }

    // ---- build A fragments into LDS (each wave packs TPS/WPB = 4 tiles) ----
    const float* __restrict__ tgt = z ? p0 : p1;
    #pragma unroll
    for (int lt = 0; lt < TPS / WPB; ++lt) {
        int t = wave * (TPS / WPB) + lt;
        int j = (seg * TPS + t) * 32 + r;
        float x = tgt[3*j], y = tgt[3*j+1], zc = tgt[3*j+2];
        _Float16 xh = (_Float16)x, yh = (_Float16)y, zh = (_Float16)zc;
        _Float16 xl = (_Float16)(x  - (float)xh);
        _Float16 yl = (_Float16)(y  - (float)yh);
        _Float16 zl = (_Float16)(zc - (float)zh);
        float w = -0.5f * (x*x + y*y + zc*zc);
        _Float16 wh = (_Float16)w, wl = (_Float16)(w - (float)wh);
        f16x8 o;
        if (!hi) { o[0]=xh; o[1]=yh; o[2]=zh; o[3]=xh; o[4]=yh; o[5]=zh; o[6]=xl; o[7]=yl; }
        else {
            o[0]=zl; o[1]=wh; o[2]=wl;
            o[3]=(_Float16)0.0f; o[4]=(_Float16)0.0f; o[5]=(_Float16)0.0f;
            o[6]=(_Float16)0.0f; o[7]=(_Float16)0.0f;
        }
        Alds[t * 64 + lane] = o;
    }
    __syncthreads();

    // ---- MFMA loop: groups of 4 independent MFMAs, then fold ----
    float m[BPT][4];
    #pragma unroll
    for (int c = 0; c < BPT; ++c)
        #pragma unroll
        for (int p = 0; p < 4; ++p) m[c][p] = -3.0e38f;

    const f32x16 zero = {};
    f16x8 a = Alds[lane];

#define FOLD(c, d)                                                  \
    _Pragma("unroll")                                               \
    for (int p = 0; p < 4; ++p) {                                   \
        m[c][p] = fmaxf(fmaxf(m[c][p], d[4*p  ]), d[4*p+1]);        \
        m[c][p] = fmaxf(fmaxf(m[c][p], d[4*p+2]), d[4*p+3]);        \
    }

    for (int t = 0; t < TPS; ++t) {
        f16x8 a_cur = a;
        int tn = (t + 1 < TPS) ? t + 1 : t;
        a = Alds[tn * 64 + lane];              // prefetch next A-frag
        // group 0: 4 MFMAs in flight before any fold touches their results
        f32x16 d0 = __builtin_amdgcn_mfma_f32_32x32x16_f16(a_cur, b[0], zero, 0, 0, 0);
        f32x16 d1 = __builtin_amdgcn_mfma_f32_32x32x16_f16(a_cur, b[1], zero, 0, 0, 0);
        f32x16 d2 = __builtin_amdgcn_mfma_f32_32x32x16_f16(a_cur, b[2], zero, 0, 0, 0);
        f32x16 d3 = __builtin_amdgcn_mfma_f32_32x32x16_f16(a_cur, b[3], zero, 0, 0, 0);
        FOLD(0, d0) FOLD(1, d1) FOLD(2, d2) FOLD(3, d3)
        // group 1
        f32x16 d4 = __builtin_amdgcn_mfma_f32_32x32x16_f16(a_cur, b[4], zero, 0, 0, 0);
        f32x16 d5 = __builtin_amdgcn_mfma_f32_32x32x16_f16(a_cur, b[5], zero, 0, 0, 0);
        f32x16 d6 = __builtin_amdgcn_mfma_f32_32x32x16_f16(a_cur, b[6], zero, 0, 0, 0);
        f32x16 d7 = __builtin_amdgcn_mfma_f32_32x32x16_f16(a_cur, b[7], zero, 0, 0, 0);
        FOLD(4, d4) FOLD(5, d5) FOLD(6, d6) FOLD(7, d7)
    }
#undef FOLD

    #pragma unroll
    for (int c = 0; c < BPT; ++c) {
        float v = fmaxf(fmaxf(m[c][0], m[c][1]), fmaxf(m[c][2], m[c][3]));
        v = fmaxf(v, __shfl_xor(v, 32, 64));   // fold the two row-halves
        if (lane < 32) P[(size_t)seg * N + col * (32 * BPT) + c * 32 + lane] = v;
    }
}

// ---------------------------------------------------------------------------
// Combine segment maxima, form truncated chamfer per query, mean-reduce.
// (identical to R4/R5 — absmax 0.0)
// ---------------------------------------------------------------------------
__global__ __launch_bounds__(256) void reduce_kernel(
    const float* __restrict__ fw, const float* __restrict__ bwv,
    const float* __restrict__ p0,
    const float* __restrict__ Pfw, const float* __restrict__ Pbw,
    float* __restrict__ out, int N, float inv) {
    int z = blockIdx.z;
    const float* __restrict__ part = z ? Pbw : Pfw;

    int i = blockIdx.x * blockDim.x + threadIdx.x;
    float c = 0.0f;
    if (i < N) {
        float qx = p0[3*i]   + fw[3*i];
        float qy = p0[3*i+1] + fw[3*i+1];
        float qz = p0[3*i+2] + fw[3*i+2];
        if (z) { qx -= bwv[3*i]; qy -= bwv[3*i+1]; qz -= bwv[3*i+2]; }
        float q2 = qx*qx + qy*qy + qz*qz;
        float mv = -3.0e38f;
        #pragma unroll
        for (int s = 0; s < NSEG; ++s) mv = fmaxf(mv, part[(size_t)s * N + i]);
        float d2 = fmaf(-2.0f, mv, q2);        // ||q||^2 - 2*max = min sq dist
        d2 = fmaxf(d2, 0.0f);
        c = fminf(d2, TRUNC_VAL);
    }
    #pragma unroll
    for (int off = 32; off > 0; off >>= 1) c += __shfl_down(c, off, 64);
    __shared__ float wsum[256 / 64];
    int lane = threadIdx.x & 63, wid = threadIdx.x >> 6;
    if (lane == 0) wsum[wid] = c;
    __syncthreads();
    if (threadIdx.x == 0) {
        float s = 0.0f;
        #pragma unroll
        for (int w = 0; w < 256 / 64; ++w) s += wsum[w];
        atomicAdd(out, s * inv);
    }
}

extern "C" void kernel_launch(void* const* d_in, const int* in_sizes, int n_in,
                              void* d_out, int out_size, void* d_ws, size_t ws_size,
                              hipStream_t stream) {
    const float* fw  = (const float*)d_in[0];  // fw_flow_pred [N,3]
    const float* bwv = (const float*)d_in[1];  // bw_flow_pred [N,3]
    const float* p0  = (const float*)d_in[2];  // pcl_0 [N,3]
    const float* p1  = (const float*)d_in[3];  // pcl_1 [M,3]
    int N = in_sizes[0] / 3;                   // 16384; M == N for this problem
    int ncol = N / (32 * BPT);                 // 64 query columns

    float* out = (float*)d_out;
    char* w = (char*)d_ws;
    float* Pfw = (float*)w;                    w += (size_t)NSEG * N * 4;
    float* Pbw = (float*)w;

    dim3 grid(ncol / WPB, NSEG, 2);            // (16, 32, 2) = 1024 blocks
    chamfer_mfma_kernel<<<grid, 64 * WPB, 0, stream>>>(
        fw, bwv, p0, p1, Pfw, Pbw, out, N);

    dim3 rgrid((N + 255) / 256, 1, 2);
    reduce_kernel<<<rgrid, 256, 0, stream>>>(
        fw, bwv, p0, Pfw, Pbw, out, N, 1.0f / N);
}

// Round 7
// 31.346 us; speedup vs baseline: 1.2080x; 1.2080x over previous
//
#include <hip/hip_runtime.h>

typedef _Float16 f16x8 __attribute__((ext_vector_type(8)));
typedef float f32x16 __attribute__((ext_vector_type(16)));

#define TRUNC_VAL 2.0f
#define TPS 16     // A-tiles per segment (LDS-resident); NSEG = NT/TPS
#define NSEG 32    // segments for N=16384
#define WPB 4      // waves per block
#define BPT 8      // query (B) tiles per wave: 8 MFMAs per A-frag read

// ---------------------------------------------------------------------------
// R7 = R5 (proven 30.7us, absmax 0.0) + ONE change: the zero C-operand is
// made opaque via an empty asm barrier so the compiler keeps it in 16 live
// VGPRs instead of re-materializing it per MFMA (R4/R6 counter forensics:
// VALUBusy 54% = 22.6us issued VALU vs ~5us algorithmic — the excess is
// zero-remat + AGPR shuttling; the 88-VGPR (256,1)/no-hint schedules put
// accumulators in AGPRs, costing ~32 extra VALU ops per MFMA).
// KEEP __launch_bounds__(256,2): R6 proved (256,1) makes the compiler
// regenerate the bad 88-VGPR AGPR schedule (-23%).
// R2 lesson: no device-scope fences. R3/R4 lesson: launch count immaterial.
//
// Fragment layout (identical values to the verified pack, absmax 0.0):
//   v_mfma_f32_32x32x16_f16, lane l of tile t at frag[t*64+l],
//   row/col = l&31, k = 8*(l>>5)+i.  hi/lo fp16 split, ~22-bit precision:
//   A (target j): [xh yh zh | xh yh zh | xl yl zl | wh wl | 0...] w=-0.5||y||^2
//   B (query  i): [xh yh zh | xl yl zl | xh yh zh | 1  1  | 0...]
//   => dot = q.y - 0.5||y||^2
// ---------------------------------------------------------------------------
__global__ __launch_bounds__(64 * WPB, 2) void chamfer_mfma_kernel(
    const float* __restrict__ fw, const float* __restrict__ bwv,
    const float* __restrict__ p0, const float* __restrict__ p1,
    float* __restrict__ Pfw, float* __restrict__ Pbw,
    float* __restrict__ out, int N) {
    __shared__ f16x8 Alds[TPS * 64];           // 16 KB: the block's A segment

    int lane = threadIdx.x & 63;
    int wave = threadIdx.x >> 6;
    int r    = lane & 31;
    bool hi  = lane >= 32;
    int col  = blockIdx.x * WPB + wave;        // query column: 256 queries/wave
    int seg  = blockIdx.y;                     // target segment (block-shared)
    int z    = blockIdx.z;
    float* __restrict__ P = z ? Pbw : Pfw;

    // out[0] = 0 once per launch; stream-ordered before reduce's atomicAdds.
    if (threadIdx.x == 0 && blockIdx.x == 0 && blockIdx.y == 0 && z == 0)
        out[0] = 0.0f;

    // ---- build B fragments in registers (once per wave) ----
    f16x8 b[BPT];
    #pragma unroll
    for (int c = 0; c < BPT; ++c) {
        int i = (col * BPT + c) * 32 + r;
        float qx = p0[3*i]   + fw[3*i];
        float qy = p0[3*i+1] + fw[3*i+1];
        float qz = p0[3*i+2] + fw[3*i+2];
        if (z) { qx -= bwv[3*i]; qy -= bwv[3*i+1]; qz -= bwv[3*i+2]; }
        _Float16 xh = (_Float16)qx, yh = (_Float16)qy, zh = (_Float16)qz;
        _Float16 xl = (_Float16)(qx - (float)xh);
        _Float16 yl = (_Float16)(qy - (float)yh);
        _Float16 zl = (_Float16)(qz - (float)zh);
        f16x8 o;
        if (!hi) { o[0]=xh; o[1]=yh; o[2]=zh; o[3]=xl; o[4]=yl; o[5]=zl; o[6]=xh; o[7]=yh; }
        else {
            o[0]=zh; o[1]=(_Float16)1.0f; o[2]=(_Float16)1.0f;
            o[3]=(_Float16)0.0f; o[4]=(_Float16)0.0f; o[5]=(_Float16)0.0f;
            o[6]=(_Float16)0.0f; o[7]=(_Float16)0.0f;
        }
        b[c] = o;
    }

    // ---- build A fragments into LDS (each wave packs TPS/WPB = 4 tiles) ----
    const float* __restrict__ tgt = z ? p0 : p1;
    #pragma unroll
    for (int lt = 0; lt < TPS / WPB; ++lt) {
        int t = wave * (TPS / WPB) + lt;
        int j = (seg * TPS + t) * 32 + r;
        float x = tgt[3*j], y = tgt[3*j+1], zc = tgt[3*j+2];
        _Float16 xh = (_Float16)x, yh = (_Float16)y, zh = (_Float16)zc;
        _Float16 xl = (_Float16)(x  - (float)xh);
        _Float16 yl = (_Float16)(y  - (float)yh);
        _Float16 zl = (_Float16)(zc - (float)zh);
        float w = -0.5f * (x*x + y*y + zc*zc);
        _Float16 wh = (_Float16)w, wl = (_Float16)(w - (float)wh);
        f16x8 o;
        if (!hi) { o[0]=xh; o[1]=yh; o[2]=zh; o[3]=xh; o[4]=yh; o[5]=zh; o[6]=xl; o[7]=yl; }
        else {
            o[0]=zl; o[1]=wh; o[2]=wl;
            o[3]=(_Float16)0.0f; o[4]=(_Float16)0.0f; o[5]=(_Float16)0.0f;
            o[6]=(_Float16)0.0f; o[7]=(_Float16)0.0f;
        }
        Alds[t * 64 + lane] = o;
    }
    __syncthreads();

    // ---- MFMA loop: groups of 4 independent MFMAs, then fold ----
    float m[BPT][4];
    #pragma unroll
    for (int c = 0; c < BPT; ++c)
        #pragma unroll
        for (int p = 0; p < 4; ++p) m[c][p] = -3.0e38f;

    // Opaque zero: the compiler must keep these 16 VGPRs live and feed every
    // MFMA from them — it can no longer re-materialize the zero C per MFMA
    // (the VALU bloat R4/R6's counters exposed).  Runtime value is still 0.
    f32x16 zero = {};
    asm volatile("" : "+v"(zero));

    f16x8 a = Alds[lane];

#define FOLD(c, d)                                                  \
    _Pragma("unroll")                                               \
    for (int p = 0; p < 4; ++p) {                                   \
        m[c][p] = fmaxf(fmaxf(m[c][p], d[4*p  ]), d[4*p+1]);        \
        m[c][p] = fmaxf(fmaxf(m[c][p], d[4*p+2]), d[4*p+3]);        \
    }

    for (int t = 0; t < TPS; ++t) {
        f16x8 a_cur = a;
        int tn = (t + 1 < TPS) ? t + 1 : t;
        a = Alds[tn * 64 + lane];              // prefetch next A-frag
        // group 0: 4 MFMAs in flight before any fold touches their results
        f32x16 d0 = __builtin_amdgcn_mfma_f32_32x32x16_f16(a_cur, b[0], zero, 0, 0, 0);
        f32x16 d1 = __builtin_amdgcn_mfma_f32_32x32x16_f16(a_cur, b[1], zero, 0, 0, 0);
        f32x16 d2 = __builtin_amdgcn_mfma_f32_32x32x16_f16(a_cur, b[2], zero, 0, 0, 0);
        f32x16 d3 = __builtin_amdgcn_mfma_f32_32x32x16_f16(a_cur, b[3], zero, 0, 0, 0);
        FOLD(0, d0) FOLD(1, d1) FOLD(2, d2) FOLD(3, d3)
        // group 1
        f32x16 d4 = __builtin_amdgcn_mfma_f32_32x32x16_f16(a_cur, b[4], zero, 0, 0, 0);
        f32x16 d5 = __builtin_amdgcn_mfma_f32_32x32x16_f16(a_cur, b[5], zero, 0, 0, 0);
        f32x16 d6 = __builtin_amdgcn_mfma_f32_32x32x16_f16(a_cur, b[6], zero, 0, 0, 0);
        f32x16 d7 = __builtin_amdgcn_mfma_f32_32x32x16_f16(a_cur, b[7], zero, 0, 0, 0);
        FOLD(4, d4) FOLD(5, d5) FOLD(6, d6) FOLD(7, d7)
    }
#undef FOLD

    #pragma unroll
    for (int c = 0; c < BPT; ++c) {
        float v = fmaxf(fmaxf(m[c][0], m[c][1]), fmaxf(m[c][2], m[c][3]));
        v = fmaxf(v, __shfl_xor(v, 32, 64));   // fold the two row-halves
        if (lane < 32) P[(size_t)seg * N + col * (32 * BPT) + c * 32 + lane] = v;
    }
}

// ---------------------------------------------------------------------------
// Combine segment maxima, form truncated chamfer per query, mean-reduce.
// (identical to R4/R5 — absmax 0.0)
// ---------------------------------------------------------------------------
__global__ __launch_bounds__(256) void reduce_kernel(
    const float* __restrict__ fw, const float* __restrict__ bwv,
    const float* __restrict__ p0,
    const float* __restrict__ Pfw, const float* __restrict__ Pbw,
    float* __restrict__ out, int N, float inv) {
    int z = blockIdx.z;
    const float* __restrict__ part = z ? Pbw : Pfw;

    int i = blockIdx.x * blockDim.x + threadIdx.x;
    float c = 0.0f;
    if (i < N) {
        float qx = p0[3*i]   + fw[3*i];
        float qy = p0[3*i+1] + fw[3*i+1];
        float qz = p0[3*i+2] + fw[3*i+2];
        if (z) { qx -= bwv[3*i]; qy -= bwv[3*i+1]; qz -= bwv[3*i+2]; }
        float q2 = qx*qx + qy*qy + qz*qz;
        float mv = -3.0e38f;
        #pragma unroll
        for (int s = 0; s < NSEG; ++s) mv = fmaxf(mv, part[(size_t)s * N + i]);
        float d2 = fmaf(-2.0f, mv, q2);        // ||q||^2 - 2*max = min sq dist
        d2 = fmaxf(d2, 0.0f);
        c = fminf(d2, TRUNC_VAL);
    }
    #pragma unroll
    for (int off = 32; off > 0; off >>= 1) c += __shfl_down(c, off, 64);
    __shared__ float wsum[256 / 64];
    int lane = threadIdx.x & 63, wid = threadIdx.x >> 6;
    if (lane == 0) wsum[wid] = c;
    __syncthreads();
    if (threadIdx.x == 0) {
        float s = 0.0f;
        #pragma unroll
        for (int w = 0; w < 256 / 64; ++w) s += wsum[w];
        atomicAdd(out, s * inv);
    }
}

extern "C" void kernel_launch(void* const* d_in, const int* in_sizes, int n_in,
                              void* d_out, int out_size, void* d_ws, size_t ws_size,
                              hipStream_t stream) {
    const float* fw  = (const float*)d_in[0];  // fw_flow_pred [N,3]
    const float* bwv = (const float*)d_in[1];  // bw_flow_pred [N,3]
    const float* p0  = (const float*)d_in[2];  // pcl_0 [N,3]
    const float* p1  = (const float*)d_in[3];  // pcl_1 [M,3]
    int N = in_sizes[0] / 3;                   // 16384; M == N for this problem
    int ncol = N / (32 * BPT);                 // 64 query columns

    float* out = (float*)d_out;
    char* w = (char*)d_ws;
    float* Pfw = (float*)w;                    w += (size_t)NSEG * N * 4;
    float* Pbw = (float*)w;

    dim3 grid(ncol / WPB, NSEG, 2);            // (16, 32, 2) = 1024 blocks
    chamfer_mfma_kernel<<<grid, 64 * WPB, 0, stream>>>(
        fw, bwv, p0, p1, Pfw, Pbw, out, N);

    dim3 rgrid((N + 255) / 256, 1, 2);
    reduce_kernel<<<rgrid, 256, 0, stream>>>(
        fw, bwv, p0, Pfw, Pbw, out, N, 1.0f / N);
}

// Round 8
// 28.598 us; speedup vs baseline: 1.3241x; 1.0961x over previous
//
#include <hip/hip_runtime.h>

typedef _Float16 f16x8 __attribute__((ext_vector_type(8)));
typedef float f32x16 __attribute__((ext_vector_type(16)));

#define TRUNC_VAL 2.0f
#define TPS 16     // A-tiles per segment (LDS-resident); NSEG = NT/TPS
#define NSEG 32    // segments for N=16384
#define WPB 4      // waves per block
#define BPT 4      // query (B) tiles per wave: 4 MFMAs per A-frag read (R8)

// ---------------------------------------------------------------------------
// R8 = R5 structure with BPT 8 -> 4 (live accumulators 128 -> 64 VGPRs).
// R5 post-mortem arithmetic (corrected per-CU MFMA cost, confirmed by R4's
// MfmaUtil counter): MFMA floor 6.9us, VALU fold floor 3.4us, chamfer floor
// ~9-10us. R5's ~24us chamfer sits 2.5x above it; by elimination (R3 launch
// test, R7 zero-remat test both null) the residual is the ~240-VGPR inner
// loop parked at the (256,2) allocation boundary -> spill/AGPR-shuttle or
// group-1-behind-group-0 serialization. BPT=4 lands ~150 VGPRs: no boundary,
// ILP-4 intact, and 3 waves/SIMD occupancy (launch_bounds min is a floor,
// not a cap). Total MFMA/fold/LDS work unchanged.
// R2 lesson: no device-scope fences. R6 lesson: keep (256,2); (256,1)
// regenerates the 88-VGPR AGPR-shuttle schedule.
//
// Fragment layout (identical values to the verified pack, absmax 0.0):
//   v_mfma_f32_32x32x16_f16, lane l of tile t at frag[t*64+l],
//   row/col = l&31, k = 8*(l>>5)+i.  hi/lo fp16 split, ~22-bit precision:
//   A (target j): [xh yh zh | xh yh zh | xl yl zl | wh wl | 0...] w=-0.5||y||^2
//   B (query  i): [xh yh zh | xl yl zl | xh yh zh | 1  1  | 0...]
//   => dot = q.y - 0.5||y||^2
// ---------------------------------------------------------------------------
__global__ __launch_bounds__(64 * WPB, 2) void chamfer_mfma_kernel(
    const float* __restrict__ fw, const float* __restrict__ bwv,
    const float* __restrict__ p0, const float* __restrict__ p1,
    float* __restrict__ Pfw, float* __restrict__ Pbw,
    float* __restrict__ out, int N) {
    __shared__ f16x8 Alds[TPS * 64];           // 16 KB: the block's A segment

    int lane = threadIdx.x & 63;
    int wave = threadIdx.x >> 6;
    int r    = lane & 31;
    bool hi  = lane >= 32;
    int col  = blockIdx.x * WPB + wave;        // query column: 128 queries/wave
    int seg  = blockIdx.y;                     // target segment (block-shared)
    int z    = blockIdx.z;
    float* __restrict__ P = z ? Pbw : Pfw;

    // out[0] = 0 once per launch; stream-ordered before reduce's atomicAdds.
    if (threadIdx.x == 0 && blockIdx.x == 0 && blockIdx.y == 0 && z == 0)
        out[0] = 0.0f;

    // ---- build B fragments in registers (once per wave) ----
    f16x8 b[BPT];
    #pragma unroll
    for (int c = 0; c < BPT; ++c) {
        int i = (col * BPT + c) * 32 + r;
        float qx = p0[3*i]   + fw[3*i];
        float qy = p0[3*i+1] + fw[3*i+1];
        float qz = p0[3*i+2] + fw[3*i+2];
        if (z) { qx -= bwv[3*i]; qy -= bwv[3*i+1]; qz -= bwv[3*i+2]; }
        _Float16 xh = (_Float16)qx, yh = (_Float16)qy, zh = (_Float16)qz;
        _Float16 xl = (_Float16)(qx - (float)xh);
        _Float16 yl = (_Float16)(qy - (float)yh);
        _Float16 zl = (_Float16)(qz - (float)zh);
        f16x8 o;
        if (!hi) { o[0]=xh; o[1]=yh; o[2]=zh; o[3]=xl; o[4]=yl; o[5]=zl; o[6]=xh; o[7]=yh; }
        else {
            o[0]=zh; o[1]=(_Float16)1.0f; o[2]=(_Float16)1.0f;
            o[3]=(_Float16)0.0f; o[4]=(_Float16)0.0f; o[5]=(_Float16)0.0f;
            o[6]=(_Float16)0.0f; o[7]=(_Float16)0.0f;
        }
        b[c] = o;
    }

    // ---- build A fragments into LDS (each wave packs TPS/WPB = 4 tiles) ----
    const float* __restrict__ tgt = z ? p0 : p1;
    #pragma unroll
    for (int lt = 0; lt < TPS / WPB; ++lt) {
        int t = wave * (TPS / WPB) + lt;
        int j = (seg * TPS + t) * 32 + r;
        float x = tgt[3*j], y = tgt[3*j+1], zc = tgt[3*j+2];
        _Float16 xh = (_Float16)x, yh = (_Float16)y, zh = (_Float16)zc;
        _Float16 xl = (_Float16)(x  - (float)xh);
        _Float16 yl = (_Float16)(y  - (float)yh);
        _Float16 zl = (_Float16)(zc - (float)zh);
        float w = -0.5f * (x*x + y*y + zc*zc);
        _Float16 wh = (_Float16)w, wl = (_Float16)(w - (float)wh);
        f16x8 o;
        if (!hi) { o[0]=xh; o[1]=yh; o[2]=zh; o[3]=xh; o[4]=yh; o[5]=zh; o[6]=xl; o[7]=yl; }
        else {
            o[0]=zl; o[1]=wh; o[2]=wl;
            o[3]=(_Float16)0.0f; o[4]=(_Float16)0.0f; o[5]=(_Float16)0.0f;
            o[6]=(_Float16)0.0f; o[7]=(_Float16)0.0f;
        }
        Alds[t * 64 + lane] = o;
    }
    __syncthreads();

    // ---- MFMA loop: 4 independent MFMAs in flight, then fold ----
    float m[BPT][4];
    #pragma unroll
    for (int c = 0; c < BPT; ++c)
        #pragma unroll
        for (int p = 0; p < 4; ++p) m[c][p] = -3.0e38f;

    const f32x16 zero = {};
    f16x8 a = Alds[lane];

#define FOLD(c, d)                                                  \
    _Pragma("unroll")                                               \
    for (int p = 0; p < 4; ++p) {                                   \
        m[c][p] = fmaxf(fmaxf(m[c][p], d[4*p  ]), d[4*p+1]);        \
        m[c][p] = fmaxf(fmaxf(m[c][p], d[4*p+2]), d[4*p+3]);        \
    }

    for (int t = 0; t < TPS; ++t) {
        f16x8 a_cur = a;
        int tn = (t + 1 < TPS) ? t + 1 : t;
        a = Alds[tn * 64 + lane];              // prefetch next A-frag
        f32x16 d0 = __builtin_amdgcn_mfma_f32_32x32x16_f16(a_cur, b[0], zero, 0, 0, 0);
        f32x16 d1 = __builtin_amdgcn_mfma_f32_32x32x16_f16(a_cur, b[1], zero, 0, 0, 0);
        f32x16 d2 = __builtin_amdgcn_mfma_f32_32x32x16_f16(a_cur, b[2], zero, 0, 0, 0);
        f32x16 d3 = __builtin_amdgcn_mfma_f32_32x32x16_f16(a_cur, b[3], zero, 0, 0, 0);
        FOLD(0, d0) FOLD(1, d1) FOLD(2, d2) FOLD(3, d3)
    }
#undef FOLD

    #pragma unroll
    for (int c = 0; c < BPT; ++c) {
        float v = fmaxf(fmaxf(m[c][0], m[c][1]), fmaxf(m[c][2], m[c][3]));
        v = fmaxf(v, __shfl_xor(v, 32, 64));   // fold the two row-halves
        if (lane < 32) P[(size_t)seg * N + col * (32 * BPT) + c * 32 + lane] = v;
    }
}

// ---------------------------------------------------------------------------
// Combine segment maxima, form truncated chamfer per query, mean-reduce.
// (identical to R4/R5 — absmax 0.0)
// ---------------------------------------------------------------------------
__global__ __launch_bounds__(256) void reduce_kernel(
    const float* __restrict__ fw, const float* __restrict__ bwv,
    const float* __restrict__ p0,
    const float* __restrict__ Pfw, const float* __restrict__ Pbw,
    float* __restrict__ out, int N, float inv) {
    int z = blockIdx.z;
    const float* __restrict__ part = z ? Pbw : Pfw;

    int i = blockIdx.x * blockDim.x + threadIdx.x;
    float c = 0.0f;
    if (i < N) {
        float qx = p0[3*i]   + fw[3*i];
        float qy = p0[3*i+1] + fw[3*i+1];
        float qz = p0[3*i+2] + fw[3*i+2];
        if (z) { qx -= bwv[3*i]; qy -= bwv[3*i+1]; qz -= bwv[3*i+2]; }
        float q2 = qx*qx + qy*qy + qz*qz;
        float mv = -3.0e38f;
        #pragma unroll
        for (int s = 0; s < NSEG; ++s) mv = fmaxf(mv, part[(size_t)s * N + i]);
        float d2 = fmaf(-2.0f, mv, q2);        // ||q||^2 - 2*max = min sq dist
        d2 = fmaxf(d2, 0.0f);
        c = fminf(d2, TRUNC_VAL);
    }
    #pragma unroll
    for (int off = 32; off > 0; off >>= 1) c += __shfl_down(c, off, 64);
    __shared__ float wsum[256 / 64];
    int lane = threadIdx.x & 63, wid = threadIdx.x >> 6;
    if (lane == 0) wsum[wid] = c;
    __syncthreads();
    if (threadIdx.x == 0) {
        float s = 0.0f;
        #pragma unroll
        for (int w = 0; w < 256 / 64; ++w) s += wsum[w];
        atomicAdd(out, s * inv);
    }
}

extern "C" void kernel_launch(void* const* d_in, const int* in_sizes, int n_in,
                              void* d_out, int out_size, void* d_ws, size_t ws_size,
                              hipStream_t stream) {
    const float* fw  = (const float*)d_in[0];  // fw_flow_pred [N,3]
    const float* bwv = (const float*)d_in[1];  // bw_flow_pred [N,3]
    const float* p0  = (const float*)d_in[2];  // pcl_0 [N,3]
    const float* p1  = (const float*)d_in[3];  // pcl_1 [M,3]
    int N = in_sizes[0] / 3;                   // 16384; M == N for this problem
    int ncol = N / (32 * BPT);                 // 128 query columns

    float* out = (float*)d_out;
    char* w = (char*)d_ws;
    float* Pfw = (float*)w;                    w += (size_t)NSEG * N * 4;
    float* Pbw = (float*)w;

    dim3 grid(ncol / WPB, NSEG, 2);            // (32, 32, 2) = 2048 blocks
    chamfer_mfma_kernel<<<grid, 64 * WPB, 0, stream>>>(
        fw, bwv, p0, p1, Pfw, Pbw, out, N);

    dim3 rgrid((N + 255) / 256, 1, 2);
    reduce_kernel<<<rgrid, 256, 0, stream>>>(
        fw, bwv, p0, Pfw, Pbw, out, N, 1.0f / N);
}

// Round 9
// 28.588 us; speedup vs baseline: 1.3246x; 1.0004x over previous
//
#include <hip/hip_runtime.h>

typedef _Float16 f16x8 __attribute__((ext_vector_type(8)));
typedef float f32x16 __attribute__((ext_vector_type(16)));

#define TRUNC_VAL 2.0f
#define TPS 16     // A-tiles per segment (LDS-resident); NSEG = NT/TPS
#define NSEG 32    // segments for N=16384
#define WPB 4      // waves per block
#define BPT 4      // query (B) tiles per wave: 4 MFMAs per A-frag read

// ---------------------------------------------------------------------------
// R9 = R8 with the occupancy/ILP point moved to 4 waves/SIMD x ILP-2.
// m69 quantization: waves/SIMD steps only at VGPR {64,128,256} — R8's ~150
// regs still allocated the 256 quantum -> 2 waves/SIMD, leaving the MFMA
// pipe ~33% fed (chamfer ~21us vs 6.9us MFMA floor). ILP-2 shrinks the live
// set to ~110 regs; __launch_bounds__(256,4) forces <=128 -> 4 waves/SIMD.
// In-flight MFMAs per SIMD = 4 waves x 2 = 8: latency hidden by TLP.
// R2: no device-scope fences. R6: never (256,1). R7: zero-remat not a cost.
//
// Fragment layout (identical values to the verified pack, absmax 0.0):
//   v_mfma_f32_32x32x16_f16, lane l of tile t at frag[t*64+l],
//   row/col = l&31, k = 8*(l>>5)+i.  hi/lo fp16 split, ~22-bit precision:
//   A (target j): [xh yh zh | xh yh zh | xl yl zl | wh wl | 0...] w=-0.5||y||^2
//   B (query  i): [xh yh zh | xl yl zl | xh yh zh | 1  1  | 0...]
//   => dot = q.y - 0.5||y||^2
// ---------------------------------------------------------------------------
__global__ __launch_bounds__(64 * WPB, 4) void chamfer_mfma_kernel(
    const float* __restrict__ fw, const float* __restrict__ bwv,
    const float* __restrict__ p0, const float* __restrict__ p1,
    float* __restrict__ Pfw, float* __restrict__ Pbw,
    float* __restrict__ out, int N) {
    __shared__ f16x8 Alds[TPS * 64];           // 16 KB: the block's A segment

    int lane = threadIdx.x & 63;
    int wave = threadIdx.x >> 6;
    int r    = lane & 31;
    bool hi  = lane >= 32;
    int col  = blockIdx.x * WPB + wave;        // query column: 128 queries/wave
    int seg  = blockIdx.y;                     // target segment (block-shared)
    int z    = blockIdx.z;
    float* __restrict__ P = z ? Pbw : Pfw;

    // out[0] = 0 once per launch; stream-ordered before reduce's atomicAdds.
    if (threadIdx.x == 0 && blockIdx.x == 0 && blockIdx.y == 0 && z == 0)
        out[0] = 0.0f;

    // ---- build B fragments in registers (once per wave) ----
    f16x8 b[BPT];
    #pragma unroll
    for (int c = 0; c < BPT; ++c) {
        int i = (col * BPT + c) * 32 + r;
        float qx = p0[3*i]   + fw[3*i];
        float qy = p0[3*i+1] + fw[3*i+1];
        float qz = p0[3*i+2] + fw[3*i+2];
        if (z) { qx -= bwv[3*i]; qy -= bwv[3*i+1]; qz -= bwv[3*i+2]; }
        _Float16 xh = (_Float16)qx, yh = (_Float16)qy, zh = (_Float16)qz;
        _Float16 xl = (_Float16)(qx - (float)xh);
        _Float16 yl = (_Float16)(qy - (float)yh);
        _Float16 zl = (_Float16)(qz - (float)zh);
        f16x8 o;
        if (!hi) { o[0]=xh; o[1]=yh; o[2]=zh; o[3]=xl; o[4]=yl; o[5]=zl; o[6]=xh; o[7]=yh; }
        else {
            o[0]=zh; o[1]=(_Float16)1.0f; o[2]=(_Float16)1.0f;
            o[3]=(_Float16)0.0f; o[4]=(_Float16)0.0f; o[5]=(_Float16)0.0f;
            o[6]=(_Float16)0.0f; o[7]=(_Float16)0.0f;
        }
        b[c] = o;
    }

    // ---- build A fragments into LDS (each wave packs TPS/WPB = 4 tiles) ----
    const float* __restrict__ tgt = z ? p0 : p1;
    #pragma unroll
    for (int lt = 0; lt < TPS / WPB; ++lt) {
        int t = wave * (TPS / WPB) + lt;
        int j = (seg * TPS + t) * 32 + r;
        float x = tgt[3*j], y = tgt[3*j+1], zc = tgt[3*j+2];
        _Float16 xh = (_Float16)x, yh = (_Float16)y, zh = (_Float16)zc;
        _Float16 xl = (_Float16)(x  - (float)xh);
        _Float16 yl = (_Float16)(y  - (float)yh);
        _Float16 zl = (_Float16)(zc - (float)zh);
        float w = -0.5f * (x*x + y*y + zc*zc);
        _Float16 wh = (_Float16)w, wl = (_Float16)(w - (float)wh);
        f16x8 o;
        if (!hi) { o[0]=xh; o[1]=yh; o[2]=zh; o[3]=xh; o[4]=yh; o[5]=zh; o[6]=xl; o[7]=yl; }
        else {
            o[0]=zl; o[1]=wh; o[2]=wl;
            o[3]=(_Float16)0.0f; o[4]=(_Float16)0.0f; o[5]=(_Float16)0.0f;
            o[6]=(_Float16)0.0f; o[7]=(_Float16)0.0f;
        }
        Alds[t * 64 + lane] = o;
    }
    __syncthreads();

    // ---- MFMA loop: 2 MFMAs in flight (ILP-2), 4 waves/SIMD (TLP) ----
    float m[BPT][4];
    #pragma unroll
    for (int c = 0; c < BPT; ++c)
        #pragma unroll
        for (int p = 0; p < 4; ++p) m[c][p] = -3.0e38f;

    const f32x16 zero = {};
    f16x8 a = Alds[lane];

#define FOLD(c, d)                                                  \
    _Pragma("unroll")                                               \
    for (int p = 0; p < 4; ++p) {                                   \
        m[c][p] = fmaxf(fmaxf(m[c][p], d[4*p  ]), d[4*p+1]);        \
        m[c][p] = fmaxf(fmaxf(m[c][p], d[4*p+2]), d[4*p+3]);        \
    }

    for (int t = 0; t < TPS; ++t) {
        f16x8 a_cur = a;
        int tn = (t + 1 < TPS) ? t + 1 : t;
        a = Alds[tn * 64 + lane];              // prefetch next A-frag
        {
            f32x16 d0 = __builtin_amdgcn_mfma_f32_32x32x16_f16(a_cur, b[0], zero, 0, 0, 0);
            f32x16 d1 = __builtin_amdgcn_mfma_f32_32x32x16_f16(a_cur, b[1], zero, 0, 0, 0);
            FOLD(0, d0) FOLD(1, d1)
        }
        {
            f32x16 d2 = __builtin_amdgcn_mfma_f32_32x32x16_f16(a_cur, b[2], zero, 0, 0, 0);
            f32x16 d3 = __builtin_amdgcn_mfma_f32_32x32x16_f16(a_cur, b[3], zero, 0, 0, 0);
            FOLD(2, d2) FOLD(3, d3)
        }
    }
#undef FOLD

    #pragma unroll
    for (int c = 0; c < BPT; ++c) {
        float v = fmaxf(fmaxf(m[c][0], m[c][1]), fmaxf(m[c][2], m[c][3]));
        v = fmaxf(v, __shfl_xor(v, 32, 64));   // fold the two row-halves
        if (lane < 32) P[(size_t)seg * N + col * (32 * BPT) + c * 32 + lane] = v;
    }
}

// ---------------------------------------------------------------------------
// Combine segment maxima, form truncated chamfer per query, mean-reduce.
// (identical to R4/R5 — absmax 0.0)
// ---------------------------------------------------------------------------
__global__ __launch_bounds__(256) void reduce_kernel(
    const float* __restrict__ fw, const float* __restrict__ bwv,
    const float* __restrict__ p0,
    const float* __restrict__ Pfw, const float* __restrict__ Pbw,
    float* __restrict__ out, int N, float inv) {
    int z = blockIdx.z;
    const float* __restrict__ part = z ? Pbw : Pfw;

    int i = blockIdx.x * blockDim.x + threadIdx.x;
    float c = 0.0f;
    if (i < N) {
        float qx = p0[3*i]   + fw[3*i];
        float qy = p0[3*i+1] + fw[3*i+1];
        float qz = p0[3*i+2] + fw[3*i+2];
        if (z) { qx -= bwv[3*i]; qy -= bwv[3*i+1]; qz -= bwv[3*i+2]; }
        float q2 = qx*qx + qy*qy + qz*qz;
        float mv = -3.0e38f;
        #pragma unroll
        for (int s = 0; s < NSEG; ++s) mv = fmaxf(mv, part[(size_t)s * N + i]);
        float d2 = fmaf(-2.0f, mv, q2);        // ||q||^2 - 2*max = min sq dist
        d2 = fmaxf(d2, 0.0f);
        c = fminf(d2, TRUNC_VAL);
    }
    #pragma unroll
    for (int off = 32; off > 0; off >>= 1) c += __shfl_down(c, off, 64);
    __shared__ float wsum[256 / 64];
    int lane = threadIdx.x & 63, wid = threadIdx.x >> 6;
    if (lane == 0) wsum[wid] = c;
    __syncthreads();
    if (threadIdx.x == 0) {
        float s = 0.0f;
        #pragma unroll
        for (int w = 0; w < 256 / 64; ++w) s += wsum[w];
        atomicAdd(out, s * inv);
    }
}

extern "C" void kernel_launch(void* const* d_in, const int* in_sizes, int n_in,
                              void* d_out, int out_size, void* d_ws, size_t ws_size,
                              hipStream_t stream) {
    const float* fw  = (const float*)d_in[0];  // fw_flow_pred [N,3]
    const float* bwv = (const float*)d_in[1];  // bw_flow_pred [N,3]
    const float* p0  = (const float*)d_in[2];  // pcl_0 [N,3]
    const float* p1  = (const float*)d_in[3];  // pcl_1 [M,3]
    int N = in_sizes[0] / 3;                   // 16384; M == N for this problem
    int ncol = N / (32 * BPT);                 // 128 query columns

    float* out = (float*)d_out;
    char* w = (char*)d_ws;
    float* Pfw = (float*)w;                    w += (size_t)NSEG * N * 4;
    float* Pbw = (float*)w;

    dim3 grid(ncol / WPB, NSEG, 2);            // (32, 32, 2) = 2048 blocks
    chamfer_mfma_kernel<<<grid, 64 * WPB, 0, stream>>>(
        fw, bwv, p0, p1, Pfw, Pbw, out, N);

    dim3 rgrid((N + 255) / 256, 1, 2);
    reduce_kernel<<<rgrid, 256, 0, stream>>>(
        fw, bwv, p0, Pfw, Pbw, out, N, 1.0f / N);
}